// Round 4
// baseline (452.232 us; speedup 1.0000x reference)
//
#include <hip/hip_runtime.h>
#include <hip/hip_bf16.h>

// HQQ 4-bit linear: out = x @ dequant(W_q)^T + bias
// M=B*S=4096, K=4096, N=4096, GROUP=128 (derived from in_sizes at launch).
//
// Round 4: dtype fix. The harness delivers the reference's float16 arrays as
// FLOAT32 (header rule: "bfloat16 -> __hip_bfloat16*, else float*"), and
// d_out is float32. Rounds 1-3 NaN'd because fp32 buffers were read as bf16
// (low mantissa halves decode as NaN ~0.4% of the time).
//
// Fused single kernel, no workspace: fp32 inputs -> bf16 in staging,
// 128x128 tile, BK=64, 16x16x32 bf16 MFMA, fp32 accum, fp32 output.

typedef __bf16 bf16x8 __attribute__((ext_vector_type(8)));
typedef float f32x4 __attribute__((ext_vector_type(4)));

#define BM 128
#define BN 128
#define BK 64

__global__ __launch_bounds__(256) void hqq_gemm_fused_f32(
    const float* __restrict__ A,      // x [M,K] fp32
    const int*   __restrict__ Wq,     // [N,K] int32 in [0,16)
    const float* __restrict__ scale,  // [N,G] fp32
    const float* __restrict__ zero,   // [N,G] fp32
    const float* __restrict__ bias,   // [N]   fp32
    float*       __restrict__ C,      // [M,N] fp32
    int M, int N, int K, int G, int GROUP)
{
    __shared__ unsigned short ldsA[BM * BK];   // 16 KB, row-major [128][64]
    __shared__ unsigned short ldsB[BN * BK];   // 16 KB

    const int tid   = threadIdx.x;
    const int lane  = tid & 63;
    const int wave  = tid >> 6;
    const int waveM = wave >> 1;   // 0..1
    const int waveN = wave & 1;    // 0..1

    const int blockN0 = blockIdx.x * BN;
    const int blockM0 = blockIdx.y * BM;

    const int row16 = lane & 15;   // m/n index within a 16x16 tile
    const int quad  = lane >> 4;   // 0..3

    f32x4 acc[4][4];
#pragma unroll
    for (int i = 0; i < 4; ++i)
#pragma unroll
        for (int j = 0; j < 4; ++j)
            acc[i][j] = (f32x4){0.f, 0.f, 0.f, 0.f};

    // staging geometry: tile = 1024 chunks of 8 elements. thread t handles
    // chunks {t, t+256, t+512, t+768}; chunk -> row = chunk>>3, col = (chunk&7)*8.
    // LDS elem addr chunk*8 == row*64 + col  (row-major [128][64] bf16).
    for (int k0 = 0; k0 < K; k0 += BK) {
        // group index uniform over the k-tile: BK=64 divides GROUP=128.
        const int g = k0 / GROUP;

        int4 ra[4], rb[4];
#pragma unroll
        for (int c = 0; c < 4; ++c) {
            const int chunk = c * 256 + tid;
            const int row   = chunk >> 3;
            const int col   = (chunk & 7) * 8;

            // ---- A: 8 fp32 -> 8 bf16 ----
            const float* ap = A + (long long)(blockM0 + row) * K + k0 + col;
            const float4 a0 = *(const float4*)(ap);
            const float4 a1 = *(const float4*)(ap + 4);
            __hip_bfloat162 pa0 = __float22bfloat162_rn(make_float2(a0.x, a0.y));
            __hip_bfloat162 pa1 = __float22bfloat162_rn(make_float2(a0.z, a0.w));
            __hip_bfloat162 pa2 = __float22bfloat162_rn(make_float2(a1.x, a1.y));
            __hip_bfloat162 pa3 = __float22bfloat162_rn(make_float2(a1.z, a1.w));
            int4 da;
            __builtin_memcpy(&da.x, &pa0, 4);
            __builtin_memcpy(&da.y, &pa1, 4);
            __builtin_memcpy(&da.z, &pa2, 4);
            __builtin_memcpy(&da.w, &pa3, 4);
            ra[c] = da;

            // ---- B: 8 int32 quant values -> dequant -> 8 bf16 ----
            const int n = blockN0 + row;
            const float s  = scale[(long long)n * G + g];
            const float z  = zero [(long long)n * G + g];
            const float mz = -z * s;                  // (q - z)*s == q*s + mz
            const long long wb = (long long)n * K + k0 + col;
            const int4 q0 = *(const int4*)(Wq + wb);
            const int4 q1 = *(const int4*)(Wq + wb + 4);
            __hip_bfloat162 p0 = __float22bfloat162_rn(
                make_float2((float)q0.x * s + mz, (float)q0.y * s + mz));
            __hip_bfloat162 p1 = __float22bfloat162_rn(
                make_float2((float)q0.z * s + mz, (float)q0.w * s + mz));
            __hip_bfloat162 p2 = __float22bfloat162_rn(
                make_float2((float)q1.x * s + mz, (float)q1.y * s + mz));
            __hip_bfloat162 p3 = __float22bfloat162_rn(
                make_float2((float)q1.z * s + mz, (float)q1.w * s + mz));
            int4 db;
            __builtin_memcpy(&db.x, &p0, 4);
            __builtin_memcpy(&db.y, &p1, 4);
            __builtin_memcpy(&db.z, &p2, 4);
            __builtin_memcpy(&db.w, &p3, 4);
            rb[c] = db;
        }

        __syncthreads();   // protect LDS from previous iteration's readers
#pragma unroll
        for (int c = 0; c < 4; ++c) {
            const int chunk = c * 256 + tid;
            *(int4*)&ldsA[chunk * 8] = ra[c];
            *(int4*)&ldsB[chunk * 8] = rb[c];
        }
        __syncthreads();   // LDS tile ready

        // ---- compute: two k-steps of 32 ----
#pragma unroll
        for (int kk = 0; kk < 2; ++kk) {
            const int kOff = kk * 32 + quad * 8;
            bf16x8 av[4], bv[4];
#pragma unroll
            for (int i = 0; i < 4; ++i)
                av[i] = *(const bf16x8*)&ldsA[(waveM * 64 + i * 16 + row16) * BK + kOff];
#pragma unroll
            for (int j = 0; j < 4; ++j)
                bv[j] = *(const bf16x8*)&ldsB[(waveN * 64 + j * 16 + row16) * BK + kOff];
#pragma unroll
            for (int i = 0; i < 4; ++i)
#pragma unroll
                for (int j = 0; j < 4; ++j)
                    acc[i][j] = __builtin_amdgcn_mfma_f32_16x16x32_bf16(
                        av[i], bv[j], acc[i][j], 0, 0, 0);
        }
    }

    // ---- epilogue: C/D layout col=lane&15, row=quad*4+reg  [m89-verified] ----
    const int colBase = blockN0 + waveN * 64;
    const int rowBase = blockM0 + waveM * 64;
    float biasf[4];
#pragma unroll
    for (int j = 0; j < 4; ++j)
        biasf[j] = bias[colBase + j * 16 + row16];

#pragma unroll
    for (int i = 0; i < 4; ++i) {
        const int row0 = rowBase + i * 16 + quad * 4;
#pragma unroll
        for (int j = 0; j < 4; ++j) {
            const int col = colBase + j * 16 + row16;
#pragma unroll
            for (int r = 0; r < 4; ++r) {
                C[(long long)(row0 + r) * N + col] = acc[i][j][r] + biasf[j];
            }
        }
    }
}

extern "C" void kernel_launch(void* const* d_in, const int* in_sizes, int n_in,
                              void* d_out, int out_size, void* d_ws, size_t ws_size,
                              hipStream_t stream) {
    (void)d_ws; (void)ws_size; (void)n_in; (void)out_size;

    const float* x     = (const float*)d_in[0];
    const int*   Wq    = (const int*)d_in[1];
    const float* scale = (const float*)d_in[2];
    const float* zero  = (const float*)d_in[3];
    const float* bias  = (const float*)d_in[4];
    float*       out   = (float*)d_out;

    const int N     = in_sizes[4];            // 4096
    const int G     = in_sizes[2] / N;        // 32
    const int K     = in_sizes[1] / N;        // 4096
    const int M     = in_sizes[0] / K;        // 4096 (B*S)
    const int GROUP = K / G;                  // 128

    dim3 grid(N / BN, M / BM);
    hqq_gemm_fused_f32<<<grid, 256, 0, stream>>>(x, Wq, scale, zero, bias, out,
                                                 M, N, K, G, GROUP);
}

// Round 5
// 344.688 us; speedup vs baseline: 1.3120x; 1.3120x over previous
//
#include <hip/hip_runtime.h>
#include <hip/hip_bf16.h>

// HQQ 4-bit linear: out = x @ dequant(W_q)^T + bias
// M=B*S=4096, K=4096, N=4096, GROUP=128. All fp16 reference arrays arrive as
// FP32; output is FP32 (harness rule: only bf16 stays 16-bit).
//
// Round 5: three-kernel plan.
//   1) convert_x:  x fp32 [M,K]  -> bf16 Ad in d_ws+32MB   (memory-bound)
//   2) dequant:    Wq int32 [N,K] + fp32 scale/zero -> bf16 Wd in d_ws
//   3) m97 GEMM:   global_load_lds width-16 staging, 128x128 tile, BK=64,
//                  16x16x32 bf16 MFMA, fp32 accum, fp32 bias/output epilogue.
// Fallback: if ws_size < 64 MB, run the round-4 fused kernel (slower, no ws).

typedef __bf16 bf16x8 __attribute__((ext_vector_type(8)));
typedef float f32x4 __attribute__((ext_vector_type(4)));

#define BM 128
#define BN 128
#define BK 64

static __device__ __forceinline__ int pack_bf16x2(float a, float b) {
    __hip_bfloat162 p = __float22bfloat162_rn(make_float2(a, b));
    int r;
    __builtin_memcpy(&r, &p, 4);
    return r;
}

// ---------------- pre-pass 1: x fp32 -> bf16 ----------------
__global__ __launch_bounds__(256) void convert_x_kernel(
    const float* __restrict__ X, unsigned short* __restrict__ Ad)
{
    const long long idx = (long long)blockIdx.x * blockDim.x + threadIdx.x;
    const long long f = idx * 8;
    const float4 a0 = *(const float4*)(X + f);
    const float4 a1 = *(const float4*)(X + f + 4);
    int4 d;
    d.x = pack_bf16x2(a0.x, a0.y);
    d.y = pack_bf16x2(a0.z, a0.w);
    d.z = pack_bf16x2(a1.x, a1.y);
    d.w = pack_bf16x2(a1.z, a1.w);
    *(int4*)(Ad + f) = d;
}

// ---------------- pre-pass 2: dequant Wq -> bf16 ----------------
__global__ __launch_bounds__(256) void dequant_kernel(
    const int*   __restrict__ Wq,
    const float* __restrict__ scale,
    const float* __restrict__ zero,
    unsigned short* __restrict__ Wd,
    int K, int G, int GROUP)
{
    const long long idx = (long long)blockIdx.x * blockDim.x + threadIdx.x;
    const long long f = idx * 8;                 // 8 consecutive k-elements
    const int n = (int)(f / K);
    const int k = (int)(f - (long long)n * K);
    const int g = k / GROUP;                     // all 8 in same group (8 | GROUP)
    const float s  = scale[(long long)n * G + g];
    const float z  = zero [(long long)n * G + g];
    const float mz = -z * s;                     // (q-z)*s == q*s + mz

    const int4 q0 = *(const int4*)(Wq + f);
    const int4 q1 = *(const int4*)(Wq + f + 4);
    int4 d;
    d.x = pack_bf16x2((float)q0.x * s + mz, (float)q0.y * s + mz);
    d.y = pack_bf16x2((float)q0.z * s + mz, (float)q0.w * s + mz);
    d.z = pack_bf16x2((float)q1.x * s + mz, (float)q1.y * s + mz);
    d.w = pack_bf16x2((float)q1.z * s + mz, (float)q1.w * s + mz);
    *(int4*)(Wd + f) = d;
}

// ---------------- GEMM kernel (m97 structure) ----------------
// C[M,N] = A[M,K] * Bw[N,K]^T + bias ; 256 threads = 4 waves in a 2x2 grid,
// each wave owns a 64x64 sub-tile = 4x4 grid of 16x16 MFMA tiles.
__global__ __launch_bounds__(256, 2) void gemm_bf16_nt(
    const unsigned short* __restrict__ A,     // bf16 bits [M,K]
    const unsigned short* __restrict__ Bw,    // bf16 bits [N,K]
    const float* __restrict__ bias,           // fp32 [N]
    float*       __restrict__ C,              // fp32 [M,N]
    int M, int N, int K)
{
    __shared__ unsigned short ldsA[BM * BK];   // 16 KB, row-major [128][64]
    __shared__ unsigned short ldsB[BN * BK];   // 16 KB

    const int tid   = threadIdx.x;
    const int lane  = tid & 63;
    const int wave  = tid >> 6;
    const int waveM = wave >> 1;   // 0..1
    const int waveN = wave & 1;    // 0..1

    const int blockN0 = blockIdx.x * BN;
    const int blockM0 = blockIdx.y * BM;

    const long long aBase = (long long)blockM0 * K;
    const long long bBase = (long long)blockN0 * K;

    // staging: tile = 16 chunks x (8 rows x 64 cols); each wave owns 4 chunks.
    // Within a chunk, lane l covers row l>>3, cols (l&7)*8..+8 — matches the
    // HW lane->LDS mapping (base + lane*16B): elem ofs = chunk*512 + 8*l.
    const int rowInChunk = lane >> 3;
    const int col8       = (lane & 7) * 8;

    f32x4 acc[4][4];
#pragma unroll
    for (int i = 0; i < 4; ++i)
#pragma unroll
        for (int j = 0; j < 4; ++j)
            acc[i][j] = (f32x4){0.f, 0.f, 0.f, 0.f};

    const int row16 = lane & 15;        // m/n index within a 16x16 tile
    const int quad  = lane >> 4;        // 0..3

    for (int k0 = 0; k0 < K; k0 += BK) {
        __syncthreads();   // protect LDS from previous iteration's readers
#pragma unroll
        for (int c = 0; c < 4; ++c) {
            const int chunk = (wave << 2) | c;              // 0..15, wave-uniform
            const int row   = (chunk << 3) | rowInChunk;    // 0..127
            const unsigned short* gA = A  + aBase + (long long)row * K + k0 + col8;
            const unsigned short* gB = Bw + bBase + (long long)row * K + k0 + col8;
            __builtin_amdgcn_global_load_lds(
                (const __attribute__((address_space(1))) unsigned int*)gA,
                (__attribute__((address_space(3))) unsigned int*)&ldsA[chunk * 512],
                16, 0, 0);
            __builtin_amdgcn_global_load_lds(
                (const __attribute__((address_space(1))) unsigned int*)gB,
                (__attribute__((address_space(3))) unsigned int*)&ldsB[chunk * 512],
                16, 0, 0);
        }
        __syncthreads();   // LDS tile ready (compiler drains vmcnt before barrier)

        // ---- compute: two k-steps of 32 ----
#pragma unroll
        for (int kk = 0; kk < 2; ++kk) {
            const int kOff = kk * 32 + quad * 8;
            bf16x8 av[4], bv[4];
#pragma unroll
            for (int i = 0; i < 4; ++i)
                av[i] = *(const bf16x8*)&ldsA[(waveM * 64 + i * 16 + row16) * BK + kOff];
#pragma unroll
            for (int j = 0; j < 4; ++j)
                bv[j] = *(const bf16x8*)&ldsB[(waveN * 64 + j * 16 + row16) * BK + kOff];
#pragma unroll
            for (int i = 0; i < 4; ++i)
#pragma unroll
                for (int j = 0; j < 4; ++j)
                    acc[i][j] = __builtin_amdgcn_mfma_f32_16x16x32_bf16(
                        av[i], bv[j], acc[i][j], 0, 0, 0);
        }
    }

    // ---- epilogue: C/D layout col=lane&15, row=quad*4+reg  [m89-verified] ----
    const int colBase = blockN0 + waveN * 64;
    const int rowBase = blockM0 + waveM * 64;
    float biasf[4];
#pragma unroll
    for (int j = 0; j < 4; ++j)
        biasf[j] = bias[colBase + j * 16 + row16];

#pragma unroll
    for (int i = 0; i < 4; ++i) {
        const int row0 = rowBase + i * 16 + quad * 4;
#pragma unroll
        for (int j = 0; j < 4; ++j) {
            const int col = colBase + j * 16 + row16;
#pragma unroll
            for (int r = 0; r < 4; ++r) {
                C[(long long)(row0 + r) * N + col] = acc[i][j][r] + biasf[j];
            }
        }
    }
}

// ---------------- fallback: round-4 fused kernel (no workspace) -------------
__global__ __launch_bounds__(256) void hqq_gemm_fused_f32(
    const float* __restrict__ A,
    const int*   __restrict__ Wq,
    const float* __restrict__ scale,
    const float* __restrict__ zero,
    const float* __restrict__ bias,
    float*       __restrict__ C,
    int M, int N, int K, int G, int GROUP)
{
    __shared__ unsigned short ldsA[BM * BK];
    __shared__ unsigned short ldsB[BN * BK];

    const int tid   = threadIdx.x;
    const int lane  = tid & 63;
    const int wave  = tid >> 6;
    const int waveM = wave >> 1;
    const int waveN = wave & 1;

    const int blockN0 = blockIdx.x * BN;
    const int blockM0 = blockIdx.y * BM;

    const int row16 = lane & 15;
    const int quad  = lane >> 4;

    f32x4 acc[4][4];
#pragma unroll
    for (int i = 0; i < 4; ++i)
#pragma unroll
        for (int j = 0; j < 4; ++j)
            acc[i][j] = (f32x4){0.f, 0.f, 0.f, 0.f};

    for (int k0 = 0; k0 < K; k0 += BK) {
        const int g = k0 / GROUP;
        int4 ra[4], rb[4];
#pragma unroll
        for (int c = 0; c < 4; ++c) {
            const int chunk = c * 256 + tid;
            const int row   = chunk >> 3;
            const int col   = (chunk & 7) * 8;

            const float* ap = A + (long long)(blockM0 + row) * K + k0 + col;
            const float4 a0 = *(const float4*)(ap);
            const float4 a1 = *(const float4*)(ap + 4);
            int4 da;
            da.x = pack_bf16x2(a0.x, a0.y);
            da.y = pack_bf16x2(a0.z, a0.w);
            da.z = pack_bf16x2(a1.x, a1.y);
            da.w = pack_bf16x2(a1.z, a1.w);
            ra[c] = da;

            const int n = blockN0 + row;
            const float s  = scale[(long long)n * G + g];
            const float z  = zero [(long long)n * G + g];
            const float mz = -z * s;
            const long long wb = (long long)n * K + k0 + col;
            const int4 q0 = *(const int4*)(Wq + wb);
            const int4 q1 = *(const int4*)(Wq + wb + 4);
            int4 db;
            db.x = pack_bf16x2((float)q0.x * s + mz, (float)q0.y * s + mz);
            db.y = pack_bf16x2((float)q0.z * s + mz, (float)q0.w * s + mz);
            db.z = pack_bf16x2((float)q1.x * s + mz, (float)q1.y * s + mz);
            db.w = pack_bf16x2((float)q1.z * s + mz, (float)q1.w * s + mz);
            rb[c] = db;
        }

        __syncthreads();
#pragma unroll
        for (int c = 0; c < 4; ++c) {
            const int chunk = c * 256 + tid;
            *(int4*)&ldsA[chunk * 8] = ra[c];
            *(int4*)&ldsB[chunk * 8] = rb[c];
        }
        __syncthreads();

#pragma unroll
        for (int kk = 0; kk < 2; ++kk) {
            const int kOff = kk * 32 + quad * 8;
            bf16x8 av[4], bv[4];
#pragma unroll
            for (int i = 0; i < 4; ++i)
                av[i] = *(const bf16x8*)&ldsA[(waveM * 64 + i * 16 + row16) * BK + kOff];
#pragma unroll
            for (int j = 0; j < 4; ++j)
                bv[j] = *(const bf16x8*)&ldsB[(waveN * 64 + j * 16 + row16) * BK + kOff];
#pragma unroll
            for (int i = 0; i < 4; ++i)
#pragma unroll
                for (int j = 0; j < 4; ++j)
                    acc[i][j] = __builtin_amdgcn_mfma_f32_16x16x32_bf16(
                        av[i], bv[j], acc[i][j], 0, 0, 0);
        }
    }

    const int colBase = blockN0 + waveN * 64;
    const int rowBase = blockM0 + waveM * 64;
    float biasf[4];
#pragma unroll
    for (int j = 0; j < 4; ++j)
        biasf[j] = bias[colBase + j * 16 + row16];

#pragma unroll
    for (int i = 0; i < 4; ++i) {
        const int row0 = rowBase + i * 16 + quad * 4;
#pragma unroll
        for (int j = 0; j < 4; ++j) {
            const int col = colBase + j * 16 + row16;
#pragma unroll
            for (int r = 0; r < 4; ++r) {
                C[(long long)(row0 + r) * N + col] = acc[i][j][r] + biasf[j];
            }
        }
    }
}

extern "C" void kernel_launch(void* const* d_in, const int* in_sizes, int n_in,
                              void* d_out, int out_size, void* d_ws, size_t ws_size,
                              hipStream_t stream) {
    (void)n_in; (void)out_size;

    const float* x     = (const float*)d_in[0];
    const int*   Wq    = (const int*)d_in[1];
    const float* scale = (const float*)d_in[2];
    const float* zero  = (const float*)d_in[3];
    const float* bias  = (const float*)d_in[4];
    float*       out   = (float*)d_out;

    const int N     = in_sizes[4];            // 4096
    const int G     = in_sizes[2] / N;        // 32
    const int K     = in_sizes[1] / N;        // 4096
    const int M     = in_sizes[0] / K;        // 4096 (B*S)
    const int GROUP = K / G;                  // 128

    const size_t needWs = (size_t)N * K * 2 + (size_t)M * K * 2;  // 64 MB

    if (ws_size >= needWs) {
        unsigned short* Wd = (unsigned short*)d_ws;                        // [N,K] bf16
        unsigned short* Ad = (unsigned short*)((char*)d_ws + (size_t)N * K * 2);  // [M,K] bf16

        const long long totalW = (long long)N * K / 8;
        dequant_kernel<<<(int)(totalW / 256), 256, 0, stream>>>(Wq, scale, zero, Wd,
                                                                K, G, GROUP);
        const long long totalA = (long long)M * K / 8;
        convert_x_kernel<<<(int)(totalA / 256), 256, 0, stream>>>(x, Ad);

        dim3 grid(N / BN, M / BM);
        gemm_bf16_nt<<<grid, 256, 0, stream>>>(Ad, Wd, bias, out, M, N, K);
    } else {
        dim3 grid(N / BN, M / BM);
        hqq_gemm_fused_f32<<<grid, 256, 0, stream>>>(x, Wq, scale, zero, bias, out,
                                                     M, N, K, G, GROUP);
    }
}

// Round 6
// 295.466 us; speedup vs baseline: 1.5306x; 1.1666x over previous
//
#include <hip/hip_runtime.h>
#include <hip/hip_bf16.h>

// HQQ 4-bit linear: out = x @ dequant(W_q)^T + bias
// M=B*S=4096, K=4096, N=4096, GROUP=128. fp16 reference arrays arrive as FP32;
// output is FP32.
//
// Round 6: XOR-swizzled LDS layout to kill the 5.03e7 bank-conflict cycles
// seen in rounds 4/5. global_load_lds forces LDS slot = base + lane*16B, so
// the swizzle is applied by permuting WHICH global col-chunk each lane loads:
// LDS row r, slot j holds global chunk j ^ (r&7); readers XOR the same term.
// Per-quad fragment reads then cover all 32 banks 2x (free) instead of
// hammering one 4-bank group 16x.
//   1) dequant:   Wq int32 [N,K] + fp32 scale/zero -> bf16 Wd (2D grid, no div)
//   2) convert_x: x fp32 [M,K] -> bf16 Ad
//   3) GEMM: m97 structure + swizzle, 128x128 tile, BK=64, 16x16x32 bf16 MFMA.

typedef __bf16 bf16x8 __attribute__((ext_vector_type(8)));
typedef float f32x4 __attribute__((ext_vector_type(4)));

#define BM 128
#define BN 128
#define BK 64

static __device__ __forceinline__ int pack_bf16x2(float a, float b) {
    __hip_bfloat162 p = __float22bfloat162_rn(make_float2(a, b));
    int r;
    __builtin_memcpy(&r, &p, 4);
    return r;
}

// ---------------- pre-pass 1: x fp32 -> bf16 ----------------
__global__ __launch_bounds__(256) void convert_x_kernel(
    const float* __restrict__ X, unsigned short* __restrict__ Ad)
{
    const long long idx = (long long)blockIdx.x * blockDim.x + threadIdx.x;
    const long long f = idx * 8;
    const float4 a0 = *(const float4*)(X + f);
    const float4 a1 = *(const float4*)(X + f + 4);
    int4 d;
    d.x = pack_bf16x2(a0.x, a0.y);
    d.y = pack_bf16x2(a0.z, a0.w);
    d.z = pack_bf16x2(a1.x, a1.y);
    d.w = pack_bf16x2(a1.z, a1.w);
    *(int4*)(Ad + f) = d;
}

// ---------------- pre-pass 2: dequant Wq -> bf16 (2D grid, no int64 div) ----
__global__ __launch_bounds__(256) void dequant_kernel(
    const int*   __restrict__ Wq,
    const float* __restrict__ scale,
    const float* __restrict__ zero,
    unsigned short* __restrict__ Wd,
    int K, int G, int GROUP)
{
    const int n = blockIdx.y;
    const int k = (blockIdx.x * blockDim.x + threadIdx.x) * 8;
    const int g = k / GROUP;                     // all 8 in same group (8 | GROUP)
    const float s  = scale[(long long)n * G + g];
    const float z  = zero [(long long)n * G + g];
    const float mz = -z * s;                     // (q-z)*s == q*s + mz

    const long long f = (long long)n * K + k;
    const int4 q0 = *(const int4*)(Wq + f);
    const int4 q1 = *(const int4*)(Wq + f + 4);
    int4 d;
    d.x = pack_bf16x2((float)q0.x * s + mz, (float)q0.y * s + mz);
    d.y = pack_bf16x2((float)q0.z * s + mz, (float)q0.w * s + mz);
    d.z = pack_bf16x2((float)q1.x * s + mz, (float)q1.y * s + mz);
    d.w = pack_bf16x2((float)q1.z * s + mz, (float)q1.w * s + mz);
    *(int4*)(Wd + f) = d;
}

// ---------------- GEMM kernel (m97 structure + XOR swizzle) ----------------
// C[M,N] = A[M,K] * Bw[N,K]^T + bias ; 256 threads = 4 waves in a 2x2 grid,
// each wave owns a 64x64 sub-tile = 4x4 grid of 16x16 MFMA tiles.
__global__ __launch_bounds__(256, 2) void gemm_bf16_nt(
    const unsigned short* __restrict__ A,     // bf16 bits [M,K]
    const unsigned short* __restrict__ Bw,    // bf16 bits [N,K]
    const float* __restrict__ bias,           // fp32 [N]
    float*       __restrict__ C,              // fp32 [M,N]
    int M, int N, int K)
{
    __shared__ unsigned short ldsA[BM * BK];   // 16 KB, swizzled row-major
    __shared__ unsigned short ldsB[BN * BK];   // 16 KB

    const int tid   = threadIdx.x;
    const int lane  = tid & 63;
    const int wave  = tid >> 6;
    const int waveM = wave >> 1;   // 0..1
    const int waveN = wave & 1;    // 0..1

    const int blockN0 = blockIdx.x * BN;
    const int blockM0 = blockIdx.y * BM;

    const long long aBase = (long long)blockM0 * K;
    const long long bBase = (long long)blockN0 * K;

    // staging: 16 chunks x (8 rows x 64 cols); each wave owns 4 chunks.
    // HW lane->LDS mapping: elem ofs = chunk*512 + lane*8. Lane l covers
    // row l>>3 of the chunk; it FETCHES global col chunk (l&7)^(l>>3), so
    // LDS row r slot j holds global chunk j ^ (r&7)   [XOR swizzle].
    const int rowInChunk = lane >> 3;
    const int colChunkSw = (lane & 7) ^ rowInChunk;    // global col chunk to fetch
    const int col8       = colChunkSw * 8;

    f32x4 acc[4][4];
#pragma unroll
    for (int i = 0; i < 4; ++i)
#pragma unroll
        for (int j = 0; j < 4; ++j)
            acc[i][j] = (f32x4){0.f, 0.f, 0.f, 0.f};

    const int row16 = lane & 15;        // m/n index within a 16x16 tile
    const int quad  = lane >> 4;        // 0..3
    const int sw    = row16 & 7;        // reader-side swizzle term

    for (int k0 = 0; k0 < K; k0 += BK) {
        __syncthreads();   // protect LDS from previous iteration's readers
#pragma unroll
        for (int c = 0; c < 4; ++c) {
            const int chunk = (wave << 2) | c;              // 0..15, wave-uniform
            const int row   = (chunk << 3) | rowInChunk;    // 0..127
            const unsigned short* gA = A  + aBase + (long long)row * K + k0 + col8;
            const unsigned short* gB = Bw + bBase + (long long)row * K + k0 + col8;
            __builtin_amdgcn_global_load_lds(
                (const __attribute__((address_space(1))) unsigned int*)gA,
                (__attribute__((address_space(3))) unsigned int*)&ldsA[chunk * 512],
                16, 0, 0);
            __builtin_amdgcn_global_load_lds(
                (const __attribute__((address_space(1))) unsigned int*)gB,
                (__attribute__((address_space(3))) unsigned int*)&ldsB[chunk * 512],
                16, 0, 0);
        }
        __syncthreads();   // LDS tile ready

        // ---- compute: two k-steps of 32 ----
#pragma unroll
        for (int kk = 0; kk < 2; ++kk) {
            bf16x8 av[4], bv[4];
#pragma unroll
            for (int i = 0; i < 4; ++i) {
                const int r    = waveM * 64 + i * 16 + row16;
                const int slot = (kk * 4 + quad) ^ sw;      // swizzled read
                av[i] = *(const bf16x8*)&ldsA[r * BK + slot * 8];
            }
#pragma unroll
            for (int j = 0; j < 4; ++j) {
                const int r    = waveN * 64 + j * 16 + row16;
                const int slot = (kk * 4 + quad) ^ sw;
                bv[j] = *(const bf16x8*)&ldsB[r * BK + slot * 8];
            }
#pragma unroll
            for (int i = 0; i < 4; ++i)
#pragma unroll
                for (int j = 0; j < 4; ++j)
                    acc[i][j] = __builtin_amdgcn_mfma_f32_16x16x32_bf16(
                        av[i], bv[j], acc[i][j], 0, 0, 0);
        }
    }

    // ---- epilogue: C/D layout col=lane&15, row=quad*4+reg  [m89-verified] ----
    const int colBase = blockN0 + waveN * 64;
    const int rowBase = blockM0 + waveM * 64;
    float biasf[4];
#pragma unroll
    for (int j = 0; j < 4; ++j)
        biasf[j] = bias[colBase + j * 16 + row16];

#pragma unroll
    for (int i = 0; i < 4; ++i) {
        const int row0 = rowBase + i * 16 + quad * 4;
#pragma unroll
        for (int j = 0; j < 4; ++j) {
            const int col = colBase + j * 16 + row16;
#pragma unroll
            for (int r = 0; r < 4; ++r) {
                C[(long long)(row0 + r) * N + col] = acc[i][j][r] + biasf[j];
            }
        }
    }
}

// ---------------- fallback: fused kernel (no workspace) ---------------------
__global__ __launch_bounds__(256) void hqq_gemm_fused_f32(
    const float* __restrict__ A,
    const int*   __restrict__ Wq,
    const float* __restrict__ scale,
    const float* __restrict__ zero,
    const float* __restrict__ bias,
    float*       __restrict__ C,
    int M, int N, int K, int G, int GROUP)
{
    __shared__ unsigned short ldsA[BM * BK];
    __shared__ unsigned short ldsB[BN * BK];

    const int tid   = threadIdx.x;
    const int lane  = tid & 63;
    const int wave  = tid >> 6;
    const int waveM = wave >> 1;
    const int waveN = wave & 1;

    const int blockN0 = blockIdx.x * BN;
    const int blockM0 = blockIdx.y * BM;

    const int row16 = lane & 15;
    const int quad  = lane >> 4;

    f32x4 acc[4][4];
#pragma unroll
    for (int i = 0; i < 4; ++i)
#pragma unroll
        for (int j = 0; j < 4; ++j)
            acc[i][j] = (f32x4){0.f, 0.f, 0.f, 0.f};

    for (int k0 = 0; k0 < K; k0 += BK) {
        const int g = k0 / GROUP;
        int4 ra[4], rb[4];
#pragma unroll
        for (int c = 0; c < 4; ++c) {
            const int chunk = c * 256 + tid;
            const int row   = chunk >> 3;
            const int col   = (chunk & 7) * 8;

            const float* ap = A + (long long)(blockM0 + row) * K + k0 + col;
            const float4 a0 = *(const float4*)(ap);
            const float4 a1 = *(const float4*)(ap + 4);
            int4 da;
            da.x = pack_bf16x2(a0.x, a0.y);
            da.y = pack_bf16x2(a0.z, a0.w);
            da.z = pack_bf16x2(a1.x, a1.y);
            da.w = pack_bf16x2(a1.z, a1.w);
            ra[c] = da;

            const int n = blockN0 + row;
            const float s  = scale[(long long)n * G + g];
            const float z  = zero [(long long)n * G + g];
            const float mz = -z * s;
            const long long wb = (long long)n * K + k0 + col;
            const int4 q0 = *(const int4*)(Wq + wb);
            const int4 q1 = *(const int4*)(Wq + wb + 4);
            int4 db;
            db.x = pack_bf16x2((float)q0.x * s + mz, (float)q0.y * s + mz);
            db.y = pack_bf16x2((float)q0.z * s + mz, (float)q0.w * s + mz);
            db.z = pack_bf16x2((float)q1.x * s + mz, (float)q1.y * s + mz);
            db.w = pack_bf16x2((float)q1.z * s + mz, (float)q1.w * s + mz);
            rb[c] = db;
        }

        __syncthreads();
#pragma unroll
        for (int c = 0; c < 4; ++c) {
            const int chunk = c * 256 + tid;
            *(int4*)&ldsA[chunk * 8] = ra[c];
            *(int4*)&ldsB[chunk * 8] = rb[c];
        }
        __syncthreads();

#pragma unroll
        for (int kk = 0; kk < 2; ++kk) {
            const int kOff = kk * 32 + quad * 8;
            bf16x8 av[4], bv[4];
#pragma unroll
            for (int i = 0; i < 4; ++i)
                av[i] = *(const bf16x8*)&ldsA[(waveM * 64 + i * 16 + row16) * BK + kOff];
#pragma unroll
            for (int j = 0; j < 4; ++j)
                bv[j] = *(const bf16x8*)&ldsB[(waveN * 64 + j * 16 + row16) * BK + kOff];
#pragma unroll
            for (int i = 0; i < 4; ++i)
#pragma unroll
                for (int j = 0; j < 4; ++j)
                    acc[i][j] = __builtin_amdgcn_mfma_f32_16x16x32_bf16(
                        av[i], bv[j], acc[i][j], 0, 0, 0);
        }
    }

    const int colBase = blockN0 + waveN * 64;
    const int rowBase = blockM0 + waveM * 64;
    float biasf[4];
#pragma unroll
    for (int j = 0; j < 4; ++j)
        biasf[j] = bias[colBase + j * 16 + row16];

#pragma unroll
    for (int i = 0; i < 4; ++i) {
        const int row0 = rowBase + i * 16 + quad * 4;
#pragma unroll
        for (int j = 0; j < 4; ++j) {
            const int col = colBase + j * 16 + row16;
#pragma unroll
            for (int r = 0; r < 4; ++r) {
                C[(long long)(row0 + r) * N + col] = acc[i][j][r] + biasf[j];
            }
        }
    }
}

extern "C" void kernel_launch(void* const* d_in, const int* in_sizes, int n_in,
                              void* d_out, int out_size, void* d_ws, size_t ws_size,
                              hipStream_t stream) {
    (void)n_in; (void)out_size;

    const float* x     = (const float*)d_in[0];
    const int*   Wq    = (const int*)d_in[1];
    const float* scale = (const float*)d_in[2];
    const float* zero  = (const float*)d_in[3];
    const float* bias  = (const float*)d_in[4];
    float*       out   = (float*)d_out;

    const int N     = in_sizes[4];            // 4096
    const int G     = in_sizes[2] / N;        // 32
    const int K     = in_sizes[1] / N;        // 4096
    const int M     = in_sizes[0] / K;        // 4096 (B*S)
    const int GROUP = K / G;                  // 128

    const size_t needWs = (size_t)N * K * 2 + (size_t)M * K * 2;  // 64 MB

    if (ws_size >= needWs) {
        unsigned short* Wd = (unsigned short*)d_ws;                        // [N,K] bf16
        unsigned short* Ad = (unsigned short*)((char*)d_ws + (size_t)N * K * 2);  // [M,K] bf16

        dim3 dgrid(K / (8 * 256), N);
        dequant_kernel<<<dgrid, 256, 0, stream>>>(Wq, scale, zero, Wd, K, G, GROUP);

        const long long totalA = (long long)M * K / 8;
        convert_x_kernel<<<(int)(totalA / 256), 256, 0, stream>>>(x, Ad);

        dim3 grid(N / BN, M / BM);
        gemm_bf16_nt<<<grid, 256, 0, stream>>>(Ad, Wd, bias, out, M, N, K);
    } else {
        dim3 grid(N / BN, M / BM);
        hqq_gemm_fused_f32<<<grid, 256, 0, stream>>>(x, Wq, scale, zero, bias, out,
                                                     M, N, K, G, GROUP);
    }
}